// Round 5
// baseline (361.386 us; speedup 1.0000x reference)
//
#include <hip/hip_runtime.h>
#include <hip/hip_fp16.h>
#include <math.h>

#define NN    128          // total nodes
#define SPB   128          // samples per block in main (2 per lane, packed f16x2)
#define SCAP  1056         // schedule slot capacity
#define RT_F  0x10000      // root flag in pcode
#define SK_F  0x20000      // skip flag (replica/padding slot)

// u32 LDS word (2 packed f16 samples) swizzle: word(n,t) at n*64 + (t ^ (n&31)).
// compute phase (n uniform): 64 consecutive words -> 2 lanes/bank, free.
// epilogue (t ~fixed, n varies): bank spread by n&31.
#define WIDX(n,t) ((n)*64 + ((t) ^ ((n)&31)))

// ws layout:
//   [0,     16896)  float4 wtab[SCAP]   {w0,w1,b,sigma} slot-ordered
//   [20480, 24704)  int    pcode[SCAP]  p0 | p1<<8 | flags<<16 | node<<24
//   [24704, 25216)  int    slotmap[128] node -> canonical slot
//   [25216, 25220)  int    S (padded slot count, multiple of 32)
//   [28672, +128K)  float  pilot_out[128][256]

// ---------------------------------------------------------------- prep+pilot
__global__ __launch_bounds__(256) void prep_pilot_kernel(
    const float* __restrict__ W, const float* __restrict__ b,
    const float* __restrict__ pm, const int* __restrict__ pidx,
    const float* __restrict__ root_pilot,
    float4* __restrict__ wtab, int* __restrict__ pcode,
    int* __restrict__ slotmap, int* __restrict__ ngp,
    float* __restrict__ pilot_out, int CAL)
{
    __shared__ _Float16 vals[NN * 256];    // 64 KB pilot tile [n*256 + j]
    __shared__ int grp[NN], slot[NN], wcnt[4];
    __shared__ int nassigned, gdone, gfin;
    const int i = threadIdx.x, w = i >> 6, lane = i & 63;

    // ---- phase 1: greedy width-8 list scheduler (threads 0..127 drive) ----
    int p0 = 0, p1 = 0, rt = 1;
    float m0 = 0.f, m1 = 0.f;
    if (i < NN) {
        m0 = pm[2*i]; m1 = pm[2*i+1];
        p0 = pidx[2*i]; p1 = pidx[2*i+1];
        rt = (m0 == 0.0f && m1 == 0.0f) ? 1 : 0;
        grp[i] = -1; slot[i] = 0;
    }
    if (i == 0) { nassigned = 0; gdone = 0; gfin = 0; }
    __syncthreads();
    for (int g = 0; g < NN; ++g) {
        int ready = (i < NN) && (grp[i] < 0) && (rt || (grp[p0] >= 0 && grp[p1] >= 0));
        unsigned long long mask = __ballot(ready);
        if (lane == 0) wcnt[w] = __popcll(mask);
        __syncthreads();
        int base = 0;
        #pragma unroll
        for (int ww = 0; ww < 4; ++ww) if (ww < w) base += wcnt[ww];
        int r = base + __popcll(mask & ((1ull << lane) - 1ull));
        if (ready && r < 8) { grp[i] = g; slot[i] = g*8 + r; }
        if (i == 0) {
            int tot = wcnt[0] + wcnt[1] + wcnt[2] + wcnt[3];
            nassigned += min(tot, 8);
            if (nassigned >= NN) { gdone = 1; gfin = g; }
        }
        __syncthreads();
        if (gdone) break;
    }
    const int S0 = 8 * (gfin + 1);
    const int S  = (S0 + 31) & ~31;
    // default-fill: skip-marked node-0 replicas
    for (int k = i; k < SCAP; k += 256) {
        pcode[k] = RT_F | SK_F;
        wtab[k]  = make_float4(0.f, 0.f, 0.f, 0.f);
    }
    __threadfence_block();
    __syncthreads();
    // canonical entries overwrite replicas (clear SK_F)
    if (i < NN) {
        pcode[slot[i]] = p0 | (p1 << 8) | (rt << 16) | (i << 24);
        wtab[slot[i]]  = make_float4(W[2*i]*m0, W[2*i+1]*m1, b[i], 0.f);
        slotmap[i] = slot[i];
    }
    if (i == 0) ngp[0] = S;
    __threadfence_block();
    __syncthreads();

    // ---- phase 2: pilot pass, thread i owns sample column jj = i ----
    const int jj = i;                          // CAL == 256
    for (int s0 = 0; s0 < S; s0 += 8) {
        int pc[8]; float4 wv[8];
        #pragma unroll
        for (int u = 0; u < 8; ++u) pc[u] = pcode[s0 + u];
        #pragma unroll
        for (int u = 0; u < 8; ++u) wv[u] = wtab[s0 + u];
        float pa[8], pb[8];
        #pragma unroll
        for (int u = 0; u < 8; ++u) {
            pa[u] = 0.f; pb[u] = 0.f;
            if (!(pc[u] & (SK_F | RT_F))) {
                int q0 = pc[u] & 0xff, q1 = (pc[u] >> 8) & 0xff;
                pa[u] = (float)vals[q0 * 256 + jj];
                pb[u] = (float)vals[q1 * 256 + jj];
            }
        }
        #pragma unroll
        for (int u = 0; u < 8; ++u) {
            if (pc[u] & SK_F) continue;        // wave-uniform skip
            int node = (pc[u] >> 24) & 0xff;
            float v;
            if (pc[u] & RT_F) {
                v = root_pilot[node * CAL + jj];
            } else {
                v = fmaxf(fmaf(wv[u].x, pa[u], fmaf(wv[u].y, pb[u], wv[u].z)), 0.0f);
            }
            if (!isfinite(v)) v = 0.0f;
            vals[node * 256 + jj] = (_Float16)v;
            pilot_out[node * CAL + jj] = v;
        }
    }
}

// ---------------------------------------------------------------- quant
__global__ __launch_bounds__(256) void quant_kernel(
    const float* __restrict__ pilot, const int* __restrict__ slotmap,
    float4* __restrict__ wtab, int CAL)
{
    __shared__ float s[256];
    const int tid = threadIdx.x;
    const int node = blockIdx.x;
    s[tid] = pilot[(size_t)node * CAL + tid];
    __syncthreads();
    for (int k = 2; k <= 256; k <<= 1) {
        for (int jj = k >> 1; jj > 0; jj >>= 1) {
            int ixj = tid ^ jj;
            if (ixj > tid) {
                float a = s[tid], bv = s[ixj];
                bool up = ((tid & k) == 0);
                if ((a > bv) == up) { s[tid] = bv; s[ixj] = a; }
            }
            __syncthreads();
        }
    }
    if (tid == 0) {
        float q25 = s[63]  + 0.75f * (s[64]  - s[63]);
        float q75 = s[191] + 0.25f * (s[192] - s[191]);
        ((float*)&wtab[slotmap[node]])[3] = 0.1f * fmaxf(q75 - q25, 1e-6f);
    }
}

// ---------------------------------------------------------------- main
// 2 samples per lane packed as f16x2 in one LDS u32; float2 z-loads; skip
// flag removes replica slots entirely (wave-uniform branch).
__device__ __forceinline__ void mk_chunk(
    int c, int P, float2 (&zb)[2][16],
    const int* __restrict__ pcode, const float4* __restrict__ wtab,
    const float* __restrict__ root_main, const float* __restrict__ z,
    unsigned NS, size_t j2, unsigned* vals, int tid)
{
    const int base = c * 16;
    // prefetch z (float2 = 2 samples) for slots [base+16, base+32)
    #pragma unroll
    for (int u = 0; u < 16; ++u) {
        int pcN = pcode[base + 16 + u];
        if (!(pcN & SK_F)) {
            const float* src = (pcN & RT_F) ? root_main : z;
            unsigned node = (unsigned)(pcN >> 24) & 0xffu;
            zb[P ^ 1][u] = *(const float2*)(src + (size_t)node * NS + j2);
        }
    }
    // two schedule groups of 8 slots each (parents strictly earlier groups)
    #pragma unroll
    for (int h = 0; h < 2; ++h) {
        int pc[8];
        #pragma unroll
        for (int u = 0; u < 8; ++u) pc[u] = pcode[base + h*8 + u];
        unsigned wa[8], wb[8];
        #pragma unroll
        for (int u = 0; u < 8; ++u) {
            wa[u] = 0u; wb[u] = 0u;
            if (!(pc[u] & (SK_F | RT_F))) {
                int q0 = pc[u] & 0xff, q1 = (pc[u] >> 8) & 0xff;
                wa[u] = vals[WIDX(q0, tid)];
                wb[u] = vals[WIDX(q1, tid)];
            }
        }
        unsigned res[8]; int nodes[8];
        #pragma unroll
        for (int u = 0; u < 8; ++u) {
            nodes[u] = (pc[u] >> 24) & 0xff;
            float4 wv = wtab[base + h*8 + u];
            float2 zv = zb[P][h*8 + u];
            float v0, v1;
            if (pc[u] & RT_F) {
                v0 = zv.x; v1 = zv.y;
            } else {
                union { unsigned u32; _Float16 h2[2]; } ua, ub;
                ua.u32 = wa[u]; ub.u32 = wb[u];
                float a0 = (float)ua.h2[0], a1 = (float)ua.h2[1];
                float b0 = (float)ub.h2[0], b1 = (float)ub.h2[1];
                v0 = fmaxf(fmaf(wv.x, a0, fmaf(wv.y, b0, wv.z)), 0.0f) + wv.w * zv.x;
                v1 = fmaxf(fmaf(wv.x, a1, fmaf(wv.y, b1, wv.z)), 0.0f) + wv.w * zv.y;
            }
            if (!isfinite(v0)) v0 = 0.0f;
            if (!isfinite(v1)) v1 = 0.0f;
            union { unsigned u32; _Float16 h2[2]; } up;
            up.h2[0] = (_Float16)v0; up.h2[1] = (_Float16)v1;
            res[u] = up.u32;
        }
        #pragma unroll
        for (int u = 0; u < 8; ++u)
            if (!(pc[u] & SK_F)) vals[WIDX(nodes[u], tid)] = res[u];
    }
}

__global__ __launch_bounds__(64) void main_kernel(
    const float4* __restrict__ wtab, const int* __restrict__ pcode,
    const int* __restrict__ ngp,
    const float* __restrict__ root_main, const float* __restrict__ z,
    const int* __restrict__ chosen, float* __restrict__ out, int NSi)
{
    __shared__ unsigned vals[NN * 64];     // 32 KB -> 5 blocks/CU
    const int tid = threadIdx.x;
    const size_t j2 = (size_t)blockIdx.x * SPB + (size_t)(tid * 2);
    const unsigned NS = (unsigned)NSi;
    const int S = ngp[0];                   // multiple of 32
    const int nch = S >> 4;                 // even chunk count

    float2 zb[2][16];
    #pragma unroll
    for (int u = 0; u < 16; ++u) {
        int pc = pcode[u];
        if (!(pc & SK_F)) {
            const float* src = (pc & RT_F) ? root_main : z;
            unsigned node = (unsigned)(pc >> 24) & 0xffu;
            zb[0][u] = *(const float2*)(src + (size_t)node * NS + j2);
        }
    }

    for (int c = 0; c < nch; c += 2) {
        mk_chunk(c,     0, zb, pcode, wtab, root_main, z, NS, j2, vals, tid);
        mk_chunk(c + 1, 1, zb, pcode, wtab, root_main, z, NS, j2, vals, tid);
    }

    __syncthreads();   // epilogue reads other lanes' columns

    // transpose epilogue: out[sample][k], float4 coalesced stores
    float4* out4 = (float4*)(out + (size_t)blockIdx.x * SPB * 64);
    #pragma unroll
    for (int it = 0; it < 32; ++it) {
        int cc = it * 64 + tid;            // float4 chunk id, 0..2047
        int s  = cc >> 4;                  // local sample 0..127
        int k0 = (cc & 15) << 2;           // chosen base
        int n0 = chosen[k0], n1 = chosen[k0+1], n2 = chosen[k0+2], n3 = chosen[k0+3];
        int tt = s >> 1, hh = s & 1;       // lane word / packed half
        union { unsigned u32; _Float16 h2[2]; } c0, c1, c2, c3;
        c0.u32 = vals[WIDX(n0, tt)];
        c1.u32 = vals[WIDX(n1, tt)];
        c2.u32 = vals[WIDX(n2, tt)];
        c3.u32 = vals[WIDX(n3, tt)];
        float4 o;
        o.x = (float)c0.h2[hh];
        o.y = (float)c1.h2[hh];
        o.z = (float)c2.h2[hh];
        o.w = (float)c3.h2[hh];
        out4[cc] = o;
    }
}

extern "C" void kernel_launch(void* const* d_in, const int* in_sizes, int n_in,
                              void* d_out, int out_size, void* d_ws, size_t ws_size,
                              hipStream_t stream) {
    const float* W          = (const float*)d_in[1];
    const float* b          = (const float*)d_in[2];
    const float* root_pilot = (const float*)d_in[3];
    const float* root_main  = (const float*)d_in[4];
    const float* z          = (const float*)d_in[5];
    const float* pm         = (const float*)d_in[6];
    const int*   pidx       = (const int*)d_in[7];
    const int*   chosen     = (const int*)d_in[9];
    float* out = (float*)d_out;

    const int NS  = in_sizes[4] / NN;   // 262144
    const int CAL = in_sizes[3] / NN;   // 256

    char* ws = (char*)d_ws;
    float4* wtab    = (float4*)ws;
    int*    pcode   = (int*)(ws + 20480);
    int*    slotmap = (int*)(ws + 24704);
    int*    ngp     = (int*)(ws + 25216);
    float*  pilot   = (float*)(ws + 28672);

    prep_pilot_kernel<<<1, 256, 0, stream>>>(W, b, pm, pidx, root_pilot,
                                             wtab, pcode, slotmap, ngp, pilot, CAL);
    quant_kernel<<<NN, 256, 0, stream>>>(pilot, slotmap, wtab, CAL);
    main_kernel <<<NS / SPB, 64, 0, stream>>>(wtab, pcode, ngp, root_main, z, chosen, out, NS);
}

// Round 6
// 359.669 us; speedup vs baseline: 1.0048x; 1.0048x over previous
//
#include <hip/hip_runtime.h>
#include <hip/hip_fp16.h>
#include <math.h>

#define NN    128          // total nodes
#define BS    64           // samples per block == threads == one wave (main)
#define SCAP  1280         // slot capacity (max S=1024 + prefetch overshoot 64+, padded)
#define RT_F  0x10000      // root flag in pcode
#define SK_F  0x20000      // skip flag (replica/padding slot)

// fp16 LDS swizzle: element (node n, lane t) at n*64 + (t ^ ((n&15)<<1)).
// compute phase (n fixed): 2-way, free; epilogue transpose: conflict-free.
#define IDX(n,t) ((n)*BS + ((t) ^ (((n)&15)<<1)))

// ws layout:
//   [0,     20480)  float4 wtab[SCAP]   {w0,w1,b,sigma} slot-ordered
//   [20480, 25600)  int    pcode[SCAP]  p0 | p1<<8 | flags<<16 | node<<24
//   [25600, 26112)  int    slotmap[128] node -> canonical slot
//   [26112, 26116)  int    S (padded slot count, multiple of 64)
//   [28672, +128K)  float  pilot_out[128][256]

// ---------------------------------------------------------------- prep+pilot
__global__ __launch_bounds__(256) void prep_pilot_kernel(
    const float* __restrict__ W, const float* __restrict__ b,
    const float* __restrict__ pm, const int* __restrict__ pidx,
    const float* __restrict__ root_pilot,
    float4* __restrict__ wtab, int* __restrict__ pcode,
    int* __restrict__ slotmap, int* __restrict__ ngp,
    float* __restrict__ pilot_out, int CAL)
{
    __shared__ _Float16 vals[NN * 256];    // 64 KB pilot tile [n*256 + j]
    __shared__ int grp[NN], slot[NN], wcnt[4];
    __shared__ int nassigned, gdone, gfin;
    const int i = threadIdx.x, w = i >> 6, lane = i & 63;

    // ---- phase 1: greedy width-8 list scheduler (threads 0..127 drive) ----
    int p0 = 0, p1 = 0, rt = 1;
    float m0 = 0.f, m1 = 0.f;
    if (i < NN) {
        m0 = pm[2*i]; m1 = pm[2*i+1];
        p0 = pidx[2*i]; p1 = pidx[2*i+1];
        rt = (m0 == 0.0f && m1 == 0.0f) ? 1 : 0;
        grp[i] = -1; slot[i] = 0;
    }
    if (i == 0) { nassigned = 0; gdone = 0; gfin = 0; }
    __syncthreads();
    for (int g = 0; g < NN; ++g) {
        int ready = (i < NN) && (grp[i] < 0) && (rt || (grp[p0] >= 0 && grp[p1] >= 0));
        unsigned long long mask = __ballot(ready);
        if (lane == 0) wcnt[w] = __popcll(mask);
        __syncthreads();
        int base = 0;
        #pragma unroll
        for (int ww = 0; ww < 4; ++ww) if (ww < w) base += wcnt[ww];
        int r = base + __popcll(mask & ((1ull << lane) - 1ull));
        if (ready && r < 8) { grp[i] = g; slot[i] = g*8 + r; }
        if (i == 0) {
            int tot = wcnt[0] + wcnt[1] + wcnt[2] + wcnt[3];
            nassigned += min(tot, 8);
            if (nassigned >= NN) { gdone = 1; gfin = g; }
        }
        __syncthreads();
        if (gdone) break;
    }
    const int S0 = 8 * (gfin + 1);
    const int S  = (S0 + 63) & ~63;        // multiple of 64 -> chunk count % 4 == 0
    // default-fill: skip-marked node-0 replicas (also covers prefetch overshoot)
    for (int k = i; k < SCAP; k += 256) {
        pcode[k] = RT_F | SK_F;
        wtab[k]  = make_float4(0.f, 0.f, 0.f, 0.f);
    }
    __threadfence_block();
    __syncthreads();
    // canonical entries overwrite replicas (clear SK_F)
    if (i < NN) {
        pcode[slot[i]] = p0 | (p1 << 8) | (rt << 16) | (i << 24);
        wtab[slot[i]]  = make_float4(W[2*i]*m0, W[2*i+1]*m1, b[i], 0.f);
        slotmap[i] = slot[i];
    }
    if (i == 0) ngp[0] = S;
    __threadfence_block();
    __syncthreads();

    // ---- phase 2: pilot pass, thread i owns sample column jj = i ----
    const int jj = i;                          // CAL == 256
    for (int s0 = 0; s0 < S; s0 += 8) {
        int pc[8]; float4 wv[8];
        #pragma unroll
        for (int u = 0; u < 8; ++u) pc[u] = pcode[s0 + u];
        #pragma unroll
        for (int u = 0; u < 8; ++u) wv[u] = wtab[s0 + u];
        float pa[8], pb[8];
        #pragma unroll
        for (int u = 0; u < 8; ++u) {
            pa[u] = 0.f; pb[u] = 0.f;
            if (!(pc[u] & (SK_F | RT_F))) {
                int q0 = pc[u] & 0xff, q1 = (pc[u] >> 8) & 0xff;
                pa[u] = (float)vals[q0 * 256 + jj];
                pb[u] = (float)vals[q1 * 256 + jj];
            }
        }
        #pragma unroll
        for (int u = 0; u < 8; ++u) {
            if (pc[u] & SK_F) continue;        // skip replicas
            int node = (pc[u] >> 24) & 0xff;
            float v;
            if (pc[u] & RT_F) {
                v = root_pilot[node * CAL + jj];
            } else {
                v = fmaxf(fmaf(wv[u].x, pa[u], fmaf(wv[u].y, pb[u], wv[u].z)), 0.0f);
            }
            if (!isfinite(v)) v = 0.0f;
            vals[node * 256 + jj] = (_Float16)v;
            pilot_out[node * CAL + jj] = v;
        }
    }
}

// ---------------------------------------------------------------- quant
__global__ __launch_bounds__(256) void quant_kernel(
    const float* __restrict__ pilot, const int* __restrict__ slotmap,
    float4* __restrict__ wtab, int CAL)
{
    __shared__ float s[256];
    const int tid = threadIdx.x;
    const int node = blockIdx.x;
    s[tid] = pilot[(size_t)node * CAL + tid];
    __syncthreads();
    for (int k = 2; k <= 256; k <<= 1) {
        for (int jj = k >> 1; jj > 0; jj >>= 1) {
            int ixj = tid ^ jj;
            if (ixj > tid) {
                float a = s[tid], bv = s[ixj];
                bool up = ((tid & k) == 0);
                if ((a > bv) == up) { s[tid] = bv; s[ixj] = a; }
            }
            __syncthreads();
        }
    }
    if (tid == 0) {
        float q25 = s[63]  + 0.75f * (s[64]  - s[63]);
        float q75 = s[191] + 0.25f * (s[192] - s[191]);
        ((float*)&wtab[slotmap[node]])[3] = 0.1f * fmaxf(q75 - q25, 1e-6f);
    }
}

// ---------------------------------------------------------------- main
// Deep software pipeline: 4 named z-chunk buffers, prefetch distance ~3 chunks
// (~1300+ busy-cycles between load issue and wait > ~900-cycle HBM latency).
// f16 per-lane LDS (16 KB -> 10 blocks/CU); SK_F skips replica slots.
__device__ __forceinline__ void pf_chunk(
    float (&zb)[16], int c,
    const int* __restrict__ pcode,
    const float* __restrict__ root_main, const float* __restrict__ z,
    unsigned NS, size_t j)
{
    const int base = c * 16;
    #pragma unroll
    for (int u = 0; u < 16; ++u) {
        int pc = pcode[base + u];
        if (!(pc & SK_F)) {
            const float* src = (pc & RT_F) ? root_main : z;
            unsigned node = (unsigned)(pc >> 24) & 0xffu;
            zb[u] = src[(size_t)(node * NS) + j];
        }
    }
}

__device__ __forceinline__ void comp_chunk(
    float (&zb)[16], int c,
    const int* __restrict__ pcode, const float4* __restrict__ wtab,
    _Float16* vals, int tid)
{
    const int base = c * 16;
    #pragma unroll
    for (int h = 0; h < 2; ++h) {          // two schedule groups of 8
        int pc[8];
        #pragma unroll
        for (int u = 0; u < 8; ++u) pc[u] = pcode[base + h*8 + u];
        float pa[8], pb[8];
        #pragma unroll
        for (int u = 0; u < 8; ++u) {
            pa[u] = 0.f; pb[u] = 0.f;
            if (!(pc[u] & (SK_F | RT_F))) {
                int q0 = pc[u] & 0xff, q1 = (pc[u] >> 8) & 0xff;
                pa[u] = (float)vals[IDX(q0, tid)];
                pb[u] = (float)vals[IDX(q1, tid)];
            }
        }
        _Float16 res[8]; int nodes[8];
        #pragma unroll
        for (int u = 0; u < 8; ++u) {
            nodes[u] = (pc[u] >> 24) & 0xff;
            float4 wv = wtab[base + h*8 + u];
            float zv = zb[h*8 + u];
            float v;
            if (pc[u] & RT_F) {
                v = zv;
            } else {
                v = fmaxf(fmaf(wv.x, pa[u], fmaf(wv.y, pb[u], wv.z)), 0.0f) + wv.w * zv;
            }
            if (!isfinite(v)) v = 0.0f;
            res[u] = (_Float16)v;
        }
        #pragma unroll
        for (int u = 0; u < 8; ++u)
            if (!(pc[u] & SK_F)) vals[IDX(nodes[u], tid)] = res[u];
    }
}

__global__ __launch_bounds__(64) void main_kernel(
    const float4* __restrict__ wtab, const int* __restrict__ pcode,
    const int* __restrict__ ngp,
    const float* __restrict__ root_main, const float* __restrict__ z,
    const int* __restrict__ chosen, float* __restrict__ out, int NSi)
{
    __shared__ _Float16 vals[NN * BS];     // 16 KB -> 10 blocks/CU
    const int tid = threadIdx.x;
    const size_t j = (size_t)blockIdx.x * BS + tid;
    const unsigned NS = (unsigned)NSi;
    const int S = ngp[0];                   // multiple of 64
    const int nch = S >> 4;                 // multiple of 4

    float zA[16], zB[16], zC[16], zD[16];
    pf_chunk(zA, 0, pcode, root_main, z, NS, j);
    pf_chunk(zB, 1, pcode, root_main, z, NS, j);
    pf_chunk(zC, 2, pcode, root_main, z, NS, j);
    pf_chunk(zD, 3, pcode, root_main, z, NS, j);

    for (int c = 0; c < nch; c += 4) {
        comp_chunk(zA, c,   pcode, wtab, vals, tid);
        pf_chunk  (zA, c+4, pcode, root_main, z, NS, j);
        comp_chunk(zB, c+1, pcode, wtab, vals, tid);
        pf_chunk  (zB, c+5, pcode, root_main, z, NS, j);
        comp_chunk(zC, c+2, pcode, wtab, vals, tid);
        pf_chunk  (zC, c+6, pcode, root_main, z, NS, j);
        comp_chunk(zD, c+3, pcode, wtab, vals, tid);
        pf_chunk  (zD, c+7, pcode, root_main, z, NS, j);
    }

    __syncthreads();   // epilogue reads other lanes' columns

    // transpose epilogue: out[sample][k], float4 coalesced stores
    float4* out4 = (float4*)(out + (size_t)blockIdx.x * BS * 64);
    #pragma unroll
    for (int it = 0; it < 16; ++it) {
        int cc = it * BS + tid;            // float4 chunk id, 0..1023
        int s  = cc >> 4;                  // local sample
        int k0 = (cc & 15) << 2;           // chosen base
        int n0 = chosen[k0], n1 = chosen[k0+1], n2 = chosen[k0+2], n3 = chosen[k0+3];
        float4 o;
        o.x = (float)vals[IDX(n0, s)];
        o.y = (float)vals[IDX(n1, s)];
        o.z = (float)vals[IDX(n2, s)];
        o.w = (float)vals[IDX(n3, s)];
        out4[cc] = o;
    }
}

extern "C" void kernel_launch(void* const* d_in, const int* in_sizes, int n_in,
                              void* d_out, int out_size, void* d_ws, size_t ws_size,
                              hipStream_t stream) {
    const float* W          = (const float*)d_in[1];
    const float* b          = (const float*)d_in[2];
    const float* root_pilot = (const float*)d_in[3];
    const float* root_main  = (const float*)d_in[4];
    const float* z          = (const float*)d_in[5];
    const float* pm         = (const float*)d_in[6];
    const int*   pidx       = (const int*)d_in[7];
    const int*   chosen     = (const int*)d_in[9];
    float* out = (float*)d_out;

    const int NS  = in_sizes[4] / NN;   // 262144
    const int CAL = in_sizes[3] / NN;   // 256

    char* ws = (char*)d_ws;
    float4* wtab    = (float4*)ws;                 // [0, 20480)
    int*    pcode   = (int*)(ws + 20480);          // [20480, 25600)
    int*    slotmap = (int*)(ws + 25600);          // [25600, 26112)
    int*    ngp     = (int*)(ws + 26112);          // [26112, 26116)
    float*  pilot   = (float*)(ws + 28672);        // [28672, +128K)

    prep_pilot_kernel<<<1, 256, 0, stream>>>(W, b, pm, pidx, root_pilot,
                                             wtab, pcode, slotmap, ngp, pilot, CAL);
    quant_kernel<<<NN, 256, 0, stream>>>(pilot, slotmap, wtab, CAL);
    main_kernel <<<NS / BS, BS, 0, stream>>>(wtab, pcode, ngp, root_main, z, chosen, out, NS);
}

// Round 7
// 358.430 us; speedup vs baseline: 1.0082x; 1.0035x over previous
//
#include <hip/hip_runtime.h>
#include <hip/hip_fp16.h>
#include <math.h>

#define NN    128          // total nodes
#define BS    64           // samples per block == threads == one wave (main)
#define SCAP  1280         // slot capacity (max S=1024 + depth-3 prefetch overshoot, padded)
#define RT_F  0x10000      // root flag in pcode
#define SK_F  0x20000      // skip flag (replica/padding slot)

// fp16 LDS swizzle: element (node n, lane t) at n*64 + (t ^ ((n&15)<<1)).
// compute phase (n fixed): 2-way, free; epilogue transpose: conflict-free.
#define IDX(n,t) ((n)*BS + ((t) ^ (((n)&15)<<1)))

// ws layout:
//   [0,     20480)  float4 wtab[SCAP]   {w0,w1,b,sigma} slot-ordered
//   [20480, 25600)  int    pcode[SCAP]  p0 | p1<<8 | flags<<16 | node<<24
//   [25600, 26112)  int    slotmap[128] node -> canonical slot
//   [26112, 26116)  int    S (padded slot count, multiple of 48)
//   [28672, +128K)  float  pilot_out[128][256]

// ---------------------------------------------------------------- prep+pilot
__global__ __launch_bounds__(256) void prep_pilot_kernel(
    const float* __restrict__ W, const float* __restrict__ b,
    const float* __restrict__ pm, const int* __restrict__ pidx,
    const float* __restrict__ root_pilot,
    float4* __restrict__ wtab, int* __restrict__ pcode,
    int* __restrict__ slotmap, int* __restrict__ ngp,
    float* __restrict__ pilot_out, int CAL)
{
    __shared__ _Float16 vals[NN * 256];    // 64 KB pilot tile [n*256 + j]
    __shared__ int grp[NN], slot[NN], wcnt[4];
    __shared__ int nassigned, gdone, gfin;
    const int i = threadIdx.x, w = i >> 6, lane = i & 63;

    // ---- phase 1: greedy width-8 list scheduler (threads 0..127 drive) ----
    int p0 = 0, p1 = 0, rt = 1;
    float m0 = 0.f, m1 = 0.f;
    if (i < NN) {
        m0 = pm[2*i]; m1 = pm[2*i+1];
        p0 = pidx[2*i]; p1 = pidx[2*i+1];
        rt = (m0 == 0.0f && m1 == 0.0f) ? 1 : 0;
        grp[i] = -1; slot[i] = 0;
    }
    if (i == 0) { nassigned = 0; gdone = 0; gfin = 0; }
    __syncthreads();
    for (int g = 0; g < NN; ++g) {
        int ready = (i < NN) && (grp[i] < 0) && (rt || (grp[p0] >= 0 && grp[p1] >= 0));
        unsigned long long mask = __ballot(ready);
        if (lane == 0) wcnt[w] = __popcll(mask);
        __syncthreads();
        int base = 0;
        #pragma unroll
        for (int ww = 0; ww < 4; ++ww) if (ww < w) base += wcnt[ww];
        int r = base + __popcll(mask & ((1ull << lane) - 1ull));
        if (ready && r < 8) { grp[i] = g; slot[i] = g*8 + r; }
        if (i == 0) {
            int tot = wcnt[0] + wcnt[1] + wcnt[2] + wcnt[3];
            nassigned += min(tot, 8);
            if (nassigned >= NN) { gdone = 1; gfin = g; }
        }
        __syncthreads();
        if (gdone) break;
    }
    const int S0 = 8 * (gfin + 1);
    const int S  = ((S0 + 47) / 48) * 48;  // multiple of 48 -> chunk count % 3 == 0
    // default-fill: skip-marked node-0 replicas (also covers prefetch overshoot)
    for (int k = i; k < SCAP; k += 256) {
        pcode[k] = RT_F | SK_F;
        wtab[k]  = make_float4(0.f, 0.f, 0.f, 0.f);
    }
    __threadfence_block();
    __syncthreads();
    // canonical entries overwrite replicas (clear SK_F)
    if (i < NN) {
        pcode[slot[i]] = p0 | (p1 << 8) | (rt << 16) | (i << 24);
        wtab[slot[i]]  = make_float4(W[2*i]*m0, W[2*i+1]*m1, b[i], 0.f);
        slotmap[i] = slot[i];
    }
    if (i == 0) ngp[0] = S;
    __threadfence_block();
    __syncthreads();

    // ---- phase 2: pilot pass, thread i owns sample column jj = i ----
    const int jj = i;                          // CAL == 256
    for (int s0 = 0; s0 < S; s0 += 8) {
        int pc[8]; float4 wv[8];
        #pragma unroll
        for (int u = 0; u < 8; ++u) pc[u] = pcode[s0 + u];
        #pragma unroll
        for (int u = 0; u < 8; ++u) wv[u] = wtab[s0 + u];
        float pa[8], pb[8];
        #pragma unroll
        for (int u = 0; u < 8; ++u) {
            pa[u] = 0.f; pb[u] = 0.f;
            if (!(pc[u] & (SK_F | RT_F))) {
                int q0 = pc[u] & 0xff, q1 = (pc[u] >> 8) & 0xff;
                pa[u] = (float)vals[q0 * 256 + jj];
                pb[u] = (float)vals[q1 * 256 + jj];
            }
        }
        #pragma unroll
        for (int u = 0; u < 8; ++u) {
            if (pc[u] & SK_F) continue;        // skip replicas
            int node = (pc[u] >> 24) & 0xff;
            float v;
            if (pc[u] & RT_F) {
                v = root_pilot[node * CAL + jj];
            } else {
                v = fmaxf(fmaf(wv[u].x, pa[u], fmaf(wv[u].y, pb[u], wv[u].z)), 0.0f);
            }
            if (!isfinite(v)) v = 0.0f;
            vals[node * 256 + jj] = (_Float16)v;
            pilot_out[node * CAL + jj] = v;
        }
    }
}

// ---------------------------------------------------------------- quant
__global__ __launch_bounds__(256) void quant_kernel(
    const float* __restrict__ pilot, const int* __restrict__ slotmap,
    float4* __restrict__ wtab, int CAL)
{
    __shared__ float s[256];
    const int tid = threadIdx.x;
    const int node = blockIdx.x;
    s[tid] = pilot[(size_t)node * CAL + tid];
    __syncthreads();
    for (int k = 2; k <= 256; k <<= 1) {
        for (int jj = k >> 1; jj > 0; jj >>= 1) {
            int ixj = tid ^ jj;
            if (ixj > tid) {
                float a = s[tid], bv = s[ixj];
                bool up = ((tid & k) == 0);
                if ((a > bv) == up) { s[tid] = bv; s[ixj] = a; }
            }
            __syncthreads();
        }
    }
    if (tid == 0) {
        float q25 = s[63]  + 0.75f * (s[64]  - s[63]);
        float q75 = s[191] + 0.25f * (s[192] - s[191]);
        ((float*)&wtab[slotmap[node]])[3] = 0.1f * fmaxf(q75 - q25, 1e-6f);
    }
}

// ---------------------------------------------------------------- main
// Depth-3 software pipeline: 3 named z-chunk register buffers, prefetch
// distance ~2-3 chunks (~700+ busy-cycles of cover vs ~900-cycle HBM
// latency). __launch_bounds__(64, 2) raises the VGPR cap to 256 so the
// allocator can actually hold the 48 z-floats in registers (R6 failure:
// default bounds -> 64-reg budget -> scratch spill, VGPR_Count stuck at 68).
__device__ __forceinline__ void pf_chunk(
    float (&zb)[16], int c,
    const int* __restrict__ pcode,
    const float* __restrict__ root_main, const float* __restrict__ z,
    unsigned NS, size_t j)
{
    const int base = c * 16;
    #pragma unroll
    for (int u = 0; u < 16; ++u) {
        int pc = pcode[base + u];
        if (!(pc & SK_F)) {
            const float* src = (pc & RT_F) ? root_main : z;
            unsigned node = (unsigned)(pc >> 24) & 0xffu;
            zb[u] = src[(size_t)(node * NS) + j];
        }
    }
}

__device__ __forceinline__ void comp_chunk(
    float (&zb)[16], int c,
    const int* __restrict__ pcode, const float4* __restrict__ wtab,
    _Float16* vals, int tid)
{
    const int base = c * 16;
    #pragma unroll
    for (int h = 0; h < 2; ++h) {          // two schedule groups of 8
        int pc[8];
        #pragma unroll
        for (int u = 0; u < 8; ++u) pc[u] = pcode[base + h*8 + u];
        float pa[8], pb[8];
        #pragma unroll
        for (int u = 0; u < 8; ++u) {
            pa[u] = 0.f; pb[u] = 0.f;
            if (!(pc[u] & (SK_F | RT_F))) {
                int q0 = pc[u] & 0xff, q1 = (pc[u] >> 8) & 0xff;
                pa[u] = (float)vals[IDX(q0, tid)];
                pb[u] = (float)vals[IDX(q1, tid)];
            }
        }
        _Float16 res[8]; int nodes[8];
        #pragma unroll
        for (int u = 0; u < 8; ++u) {
            nodes[u] = (pc[u] >> 24) & 0xff;
            float4 wv = wtab[base + h*8 + u];
            float zv = zb[h*8 + u];
            float v;
            if (pc[u] & RT_F) {
                v = zv;
            } else {
                v = fmaxf(fmaf(wv.x, pa[u], fmaf(wv.y, pb[u], wv.z)), 0.0f) + wv.w * zv;
            }
            if (!isfinite(v)) v = 0.0f;
            res[u] = (_Float16)v;
        }
        #pragma unroll
        for (int u = 0; u < 8; ++u)
            if (!(pc[u] & SK_F)) vals[IDX(nodes[u], tid)] = res[u];
    }
}

__global__ __launch_bounds__(64, 2) void main_kernel(
    const float4* __restrict__ wtab, const int* __restrict__ pcode,
    const int* __restrict__ ngp,
    const float* __restrict__ root_main, const float* __restrict__ z,
    const int* __restrict__ chosen, float* __restrict__ out, int NSi)
{
    __shared__ _Float16 vals[NN * BS];     // 16 KB -> 10 blocks/CU
    const int tid = threadIdx.x;
    const size_t j = (size_t)blockIdx.x * BS + tid;
    const unsigned NS = (unsigned)NSi;
    const int S = ngp[0];                   // multiple of 48
    const int nch = S >> 4;                 // multiple of 3

    float zA[16], zB[16], zC[16];
    pf_chunk(zA, 0, pcode, root_main, z, NS, j);
    pf_chunk(zB, 1, pcode, root_main, z, NS, j);
    pf_chunk(zC, 2, pcode, root_main, z, NS, j);

    for (int c = 0; c < nch; c += 3) {
        comp_chunk(zA, c,   pcode, wtab, vals, tid);
        pf_chunk  (zA, c+3, pcode, root_main, z, NS, j);
        comp_chunk(zB, c+1, pcode, wtab, vals, tid);
        pf_chunk  (zB, c+4, pcode, root_main, z, NS, j);
        comp_chunk(zC, c+2, pcode, wtab, vals, tid);
        pf_chunk  (zC, c+5, pcode, root_main, z, NS, j);
    }

    __syncthreads();   // epilogue reads other lanes' columns

    // transpose epilogue: out[sample][k], float4 coalesced stores
    float4* out4 = (float4*)(out + (size_t)blockIdx.x * BS * 64);
    #pragma unroll
    for (int it = 0; it < 16; ++it) {
        int cc = it * BS + tid;            // float4 chunk id, 0..1023
        int s  = cc >> 4;                  // local sample
        int k0 = (cc & 15) << 2;           // chosen base
        int n0 = chosen[k0], n1 = chosen[k0+1], n2 = chosen[k0+2], n3 = chosen[k0+3];
        float4 o;
        o.x = (float)vals[IDX(n0, s)];
        o.y = (float)vals[IDX(n1, s)];
        o.z = (float)vals[IDX(n2, s)];
        o.w = (float)vals[IDX(n3, s)];
        out4[cc] = o;
    }
}

extern "C" void kernel_launch(void* const* d_in, const int* in_sizes, int n_in,
                              void* d_out, int out_size, void* d_ws, size_t ws_size,
                              hipStream_t stream) {
    const float* W          = (const float*)d_in[1];
    const float* b          = (const float*)d_in[2];
    const float* root_pilot = (const float*)d_in[3];
    const float* root_main  = (const float*)d_in[4];
    const float* z          = (const float*)d_in[5];
    const float* pm         = (const float*)d_in[6];
    const int*   pidx       = (const int*)d_in[7];
    const int*   chosen     = (const int*)d_in[9];
    float* out = (float*)d_out;

    const int NS  = in_sizes[4] / NN;   // 262144
    const int CAL = in_sizes[3] / NN;   // 256

    char* ws = (char*)d_ws;
    float4* wtab    = (float4*)ws;                 // [0, 20480)
    int*    pcode   = (int*)(ws + 20480);          // [20480, 25600)
    int*    slotmap = (int*)(ws + 25600);          // [25600, 26112)
    int*    ngp     = (int*)(ws + 26112);          // [26112, 26116)
    float*  pilot   = (float*)(ws + 28672);        // [28672, +128K)

    prep_pilot_kernel<<<1, 256, 0, stream>>>(W, b, pm, pidx, root_pilot,
                                             wtab, pcode, slotmap, ngp, pilot, CAL);
    quant_kernel<<<NN, 256, 0, stream>>>(pilot, slotmap, wtab, CAL);
    main_kernel <<<NS / BS, BS, 0, stream>>>(wtab, pcode, ngp, root_main, z, chosen, out, NS);
}